// Round 1
// baseline (374.274 us; speedup 1.0000x reference)
//
#include <hip/hip_runtime.h>
#include <stdint.h>

// ============================================================================
// AttentionBlock: out = concat([x, softmax(QK^T/sqrt(D)) @ V], -1)
//   B=4, S=2048, D=1024, fp32 in/out.
// Strategy: f16 MFMA with 2-term (hi/lo) split emulation of fp32 on the
// Q/K/logits path (3 MFMAs per product; error ~2^-22 rel), plain f16 on the
// V/PV path. Logits sigma ~1024 -> near-one-hot softmax; split keeps logit
// error ~0.004 so no argmax flips. All matmuls use one B^T-layout GEMM
// template: 128x128 tile, BK=64, 4 waves, mfma_f32_16x16x32_f16,
// reg-staged LDS with XOR swizzle (byte ^= (row&7)<<4) for bank conflicts.
//
// ws layout (144 MiB total):
//    0 MB: Qh f16 [8192][1024]   16 MB
//   16 MB: Ql                    16 MB
//   32 MB: Kh                    16 MB
//   48 MB: Kl                    16 MB
//   64 MB: VT f16 [4][1024][2048] 16 MB   (V transposed per batch)
//   80 MB: S  f32 [4][2048][2048] 64 MB   (P f16 written in-place, row
//                                          stride stays 8192 B)
//   overlaid on S (dead before S is written):
//   80 MB: xh f16, 96 MB: xl f16, 112..122 MB: W*T hi/lo f16
// ============================================================================

typedef _Float16 h8 __attribute__((ext_vector_type(8)));
typedef _Float16 h4 __attribute__((ext_vector_type(4)));
typedef float    f4 __attribute__((ext_vector_type(4)));

// ---------------------------------------------------------------- prep ----
__global__ __launch_bounds__(256) void prep_x_split(const float* __restrict__ x,
                                                    _Float16* __restrict__ xh,
                                                    _Float16* __restrict__ xl) {
  size_t i = (size_t)blockIdx.x * 256 + threadIdx.x;  // one f4 per thread
  f4 v = ((const f4*)x)[i];
  h4 hi, lo;
#pragma unroll
  for (int j = 0; j < 4; ++j) {
    _Float16 h = (_Float16)v[j];
    hi[j] = h;
    lo[j] = (_Float16)(v[j] - (float)h);
  }
  ((h4*)xh)[i] = hi;
  ((h4*)xl)[i] = lo;
}

// W [1024][1024] row-major -> WT hi/lo [1024][1024] (transposed). lo optional.
__global__ __launch_bounds__(256) void prep_w_split(const float* __restrict__ W,
                                                    _Float16* __restrict__ WTh,
                                                    _Float16* __restrict__ WTl) {
  int i = blockIdx.x * 256 + threadIdx.x;  // [0, 1M)
  int d = i >> 10, e = i & 1023;
  float v = W[i];
  _Float16 h = (_Float16)v;
  WTh[e * 1024 + d] = h;
  if (WTl) WTl[e * 1024 + d] = (_Float16)(v - (float)h);
}

// ---------------------------------------------------------------- gemm ----
struct GemmP {
  const _Float16* Ah; const _Float16* Al;   // A [M][K] row-major (hi/lo)
  const _Float16* Bh; const _Float16* Bl;   // B [N][K] row-major (= B^T)
  long sAz, sBz;                            // per-batch element strides
  int lda, ldb, K;
  float* Cf; _Float16* Ch; _Float16* Cl;    // epilogue targets
  long sCz; int ldc; float scale;
};

enum { EPI_QK = 0, EPI_VT = 1, EPI_F32 = 2 };

template <int EPI, bool SPLIT>
__global__ __launch_bounds__(256) void gemm_bt(GemmP p) {
  constexpr int BK = 64;
  constexpr int NP = SPLIT ? 4 : 2;
  __shared__ alignas(16) _Float16 sm[NP * 128 * BK];
  _Float16* sAh = sm;
  _Float16* sBh = sm + 128 * BK;

  const int t = threadIdx.x;
  const int lane = t & 63;
  const int wave = t >> 6;
  const int wm = wave >> 1, wn = wave & 1;
  const int z = blockIdx.z;

  const size_t aBase = (size_t)z * p.sAz + (size_t)blockIdx.y * 128 * p.lda;
  const size_t bBase = (size_t)z * p.sBz + (size_t)blockIdx.x * 128 * p.ldb;

  f4 acc[4][4] = {};

  const int r0 = t >> 3;    // staging: 8 threads per 64-f16 row
  const int s16 = t & 7;    // 16B slot within row

  for (int k0 = 0; k0 < p.K; k0 += BK) {
    __syncthreads();
#pragma unroll
    for (int c = 0; c < 4; ++c) {
      int row = c * 32 + r0;
      int slot = s16 ^ (row & 7);
      int lo_ = row * BK + slot * 8;
      size_t ga = aBase + (size_t)row * p.lda + k0 + s16 * 8;
      size_t gb = bBase + (size_t)row * p.ldb + k0 + s16 * 8;
      *(h8*)&sAh[lo_] = *(const h8*)&p.Ah[ga];
      *(h8*)&sBh[lo_] = *(const h8*)&p.Bh[gb];
      if constexpr (SPLIT) {
        *(h8*)&sm[2 * 128 * BK + lo_] = *(const h8*)&p.Al[ga];
        *(h8*)&sm[3 * 128 * BK + lo_] = *(const h8*)&p.Bl[gb];
      }
    }
    __syncthreads();
#pragma unroll
    for (int ks = 0; ks < 2; ++ks) {
      h8 aH[4], bH[4], aL[4], bL[4];
#pragma unroll
      for (int m = 0; m < 4; ++m) {
        int row = wm * 64 + m * 16 + (lane & 15);
        int slot = (ks * 4 + (lane >> 4)) ^ (row & 7);
        aH[m] = *(const h8*)&sAh[row * BK + slot * 8];
        if constexpr (SPLIT) aL[m] = *(const h8*)&sm[2 * 128 * BK + row * BK + slot * 8];
      }
#pragma unroll
      for (int n = 0; n < 4; ++n) {
        int row = wn * 64 + n * 16 + (lane & 15);
        int slot = (ks * 4 + (lane >> 4)) ^ (row & 7);
        bH[n] = *(const h8*)&sBh[row * BK + slot * 8];
        if constexpr (SPLIT) bL[n] = *(const h8*)&sm[3 * 128 * BK + row * BK + slot * 8];
      }
#pragma unroll
      for (int m = 0; m < 4; ++m)
#pragma unroll
        for (int n = 0; n < 4; ++n) {
          acc[m][n] = __builtin_amdgcn_mfma_f32_16x16x32_f16(aH[m], bH[n], acc[m][n], 0, 0, 0);
          if constexpr (SPLIT) {
            acc[m][n] = __builtin_amdgcn_mfma_f32_16x16x32_f16(aH[m], bL[n], acc[m][n], 0, 0, 0);
            acc[m][n] = __builtin_amdgcn_mfma_f32_16x16x32_f16(aL[m], bH[n], acc[m][n], 0, 0, 0);
          }
        }
    }
  }

  // epilogue: C/D layout col=lane&15, row=(lane>>4)*4+reg (m89/m91 verified)
  const int gm0 = blockIdx.y * 128 + wm * 64;
  const int gn0 = blockIdx.x * 128 + wn * 64;
#pragma unroll
  for (int m = 0; m < 4; ++m) {
#pragma unroll
    for (int n = 0; n < 4; ++n) {
      int gr = gm0 + m * 16 + ((lane >> 4) << 2);
      int gc = gn0 + n * 16 + (lane & 15);
      if constexpr (EPI == EPI_QK) {
#pragma unroll
        for (int r = 0; r < 4; ++r) {
          float c = acc[m][n][r];
          _Float16 h = (_Float16)c;
          p.Ch[(size_t)(gr + r) * p.ldc + gc] = h;
          p.Cl[(size_t)(gr + r) * p.ldc + gc] = (_Float16)(c - (float)h);
        }
      } else if constexpr (EPI == EPI_VT) {
        // row gr = b*2048 + s ; col gc = d ; write VT[b][d][s] (4 contiguous s)
        int b = gr >> 11, s = gr & 2047;
        h4 hv;
#pragma unroll
        for (int r = 0; r < 4; ++r) hv[r] = (_Float16)acc[m][n][r];
        *(h4*)&p.Ch[(size_t)b * (1024 * 2048) + (size_t)gc * 2048 + s] = hv;
      } else {
#pragma unroll
        for (int r = 0; r < 4; ++r)
          p.Cf[(size_t)z * p.sCz + (size_t)(gr + r) * p.ldc + gc] = acc[m][n][r] * p.scale;
      }
    }
  }
}

// ------------------------------------------------------------- softmax ----
// One block per row (2048 f32). Reads row into regs, max/sum block-reduce,
// writes normalized P as f16 IN PLACE (bytes 0..4095 of the 8192B row).
__global__ __launch_bounds__(256) void softmax_rows(float* __restrict__ Sb) {
  const int t = threadIdx.x;
  float* row = Sb + (size_t)blockIdx.x * 2048;
  f4 v0 = ((const f4*)row)[t];
  f4 v1 = ((const f4*)row)[t + 256];
  float mx = -3.0e38f;
#pragma unroll
  for (int j = 0; j < 4; ++j) { mx = fmaxf(mx, v0[j]); mx = fmaxf(mx, v1[j]); }
#pragma unroll
  for (int o = 32; o > 0; o >>= 1) mx = fmaxf(mx, __shfl_xor(mx, o));
  __shared__ float red[4], red2[4];
  const int wave = t >> 6, lane = t & 63;
  if (lane == 0) red[wave] = mx;
  __syncthreads();
  mx = fmaxf(fmaxf(red[0], red[1]), fmaxf(red[2], red[3]));
  float pv[8];
  float sum = 0.f;
#pragma unroll
  for (int j = 0; j < 4; ++j) { pv[j] = __expf(v0[j] - mx); pv[4 + j] = __expf(v1[j] - mx); }
#pragma unroll
  for (int j = 0; j < 8; ++j) sum += pv[j];
#pragma unroll
  for (int o = 32; o > 0; o >>= 1) sum += __shfl_xor(sum, o);
  if (lane == 0) red2[wave] = sum;
  __syncthreads();   // also orders all row reads before the in-place writes
  sum = red2[0] + red2[1] + red2[2] + red2[3];
  float inv = 1.0f / sum;
  h4 o0, o1;
#pragma unroll
  for (int j = 0; j < 4; ++j) { o0[j] = (_Float16)(pv[j] * inv); o1[j] = (_Float16)(pv[4 + j] * inv); }
  _Float16* prow = (_Float16*)row;
  ((h4*)prow)[t] = o0;
  ((h4*)prow)[t + 256] = o1;
}

// ---------------------------------------------------------------- misc ----
__global__ __launch_bounds__(256) void copy_x_half(const float* __restrict__ x,
                                                   float* __restrict__ out) {
  size_t i = (size_t)blockIdx.x * 256 + threadIdx.x;  // f4 id over 2M
  size_t r = i >> 8, c = i & 255;                      // 256 f4 per x row
  ((f4*)out)[r * 512 + c] = ((const f4*)x)[i];
}

__global__ void ws_sentinel(float* out, float v) { out[0] = v; }

// -------------------------------------------------------------- launch ----
extern "C" void kernel_launch(void* const* d_in, const int* in_sizes, int n_in,
                              void* d_out, int out_size, void* d_ws, size_t ws_size,
                              hipStream_t stream) {
  const float* x  = (const float*)d_in[0];
  const float* Wq = (const float*)d_in[1];
  const float* Wk = (const float*)d_in[2];
  const float* Wv = (const float*)d_in[3];
  float* out = (float*)d_out;

  const size_t MB = 1ull << 20;
  char* w = (char*)d_ws;
  _Float16* Qh = (_Float16*)(w + 0 * MB);
  _Float16* Ql = (_Float16*)(w + 16 * MB);
  _Float16* Kh = (_Float16*)(w + 32 * MB);
  _Float16* Kl = (_Float16*)(w + 48 * MB);
  _Float16* VT = (_Float16*)(w + 64 * MB);
  float*    S  = (float*)   (w + 80 * MB);
  _Float16* xh = (_Float16*)(w + 80 * MB);   // overlays S (dead before S write)
  _Float16* xl = (_Float16*)(w + 96 * MB);
  _Float16* WqhT = (_Float16*)(w + 112 * MB);
  _Float16* WqlT = (_Float16*)(w + 114 * MB);
  _Float16* WkhT = (_Float16*)(w + 116 * MB);
  _Float16* WklT = (_Float16*)(w + 118 * MB);
  _Float16* WvhT = (_Float16*)(w + 120 * MB);

  if (ws_size < 144 * MB) {  // fail loud: absmax will report ~ws_size
    copy_x_half<<<8192, 256, 0, stream>>>(x, out);
    ws_sentinel<<<1, 1, 0, stream>>>(out, (float)ws_size);
    return;
  }

  prep_x_split<<<8192, 256, 0, stream>>>(x, xh, xl);
  prep_w_split<<<4096, 256, 0, stream>>>(Wq, WqhT, WqlT);
  prep_w_split<<<4096, 256, 0, stream>>>(Wk, WkhT, WklT);
  prep_w_split<<<4096, 256, 0, stream>>>(Wv, WvhT, (_Float16*)nullptr);

  // Q = x @ Wq, K = x @ Wk  (split, f16 hi/lo outputs)
  GemmP pq{xh, xl, WqhT, WqlT, 0, 0, 1024, 1024, 1024,
           nullptr, Qh, Ql, 0, 1024, 1.f};
  gemm_bt<EPI_QK, true><<<dim3(8, 64, 1), 256, 0, stream>>>(pq);
  GemmP pk{xh, xl, WkhT, WklT, 0, 0, 1024, 1024, 1024,
           nullptr, Kh, Kl, 0, 1024, 1.f};
  gemm_bt<EPI_QK, true><<<dim3(8, 64, 1), 256, 0, stream>>>(pk);

  // V = x @ Wv (plain f16), stored transposed per batch: VT[b][d][s]
  GemmP pv{xh, nullptr, WvhT, nullptr, 0, 0, 1024, 1024, 1024,
           nullptr, VT, nullptr, 0, 0, 1.f};
  gemm_bt<EPI_VT, false><<<dim3(8, 64, 1), 256, 0, stream>>>(pv);

  // S = (Q @ K^T) / 32   (split), fp32
  GemmP ps{Qh, Ql, Kh, Kl, 2048L * 1024, 2048L * 1024, 1024, 1024, 1024,
           S, nullptr, nullptr, 2048L * 2048, 2048, 0.03125f};
  gemm_bt<EPI_F32, true><<<dim3(16, 16, 4), 256, 0, stream>>>(ps);

  // P = softmax(S) rows, f16 in place (row stride stays 8192 B = 4096 f16)
  softmax_rows<<<8192, 256, 0, stream>>>(S);

  // attn = P @ V  -> out[:, :, 1024:2048]
  GemmP po{(const _Float16*)S, nullptr, VT, nullptr, 2048L * 4096, 1024L * 2048,
           4096, 2048, 2048, out + 1024, nullptr, nullptr,
           2048L * 2048, 2048, 1.f};
  gemm_bt<EPI_F32, false><<<dim3(8, 16, 4), 256, 0, stream>>>(po);

  // out[:, :, 0:1024] = x
  copy_x_half<<<8192, 256, 0, stream>>>(x, out);
}